// Round 8
// baseline (114.888 us; speedup 1.0000x reference)
//
#include <hip/hip_runtime.h>
#include <stdint.h>

#define N_ 256
#define H_ 1024
#define BS_ 128

// ---------------- workspace layout (floats) ----------------
// sk   : [128][1024]        @ 0          1 - tk^2
// opart: [16][3][128][256]  @ 131072     layer2 k-split partials (16 slices)
// jpart: [16][2][128][256]  @ 1703936    J h-split partials
#define WS_SK    0
#define WS_OPART 131072
#define WS_JPART 1703936
#define WS_FLOATS 2752512   // ~11 MB (harness ws is ~256 MB)

typedef __attribute__((ext_vector_type(8))) short short8v;  // 8 bf16 = 4 VGPR
typedef __attribute__((ext_vector_type(4))) float f32x4;

__device__ __forceinline__ ushort bhi(float v) {
    return (ushort)(__float_as_uint(v) >> 16);          // truncate to bf16
}
__device__ __forceinline__ float btrunc(float v) {
    return __uint_as_float(__float_as_uint(v) & 0xFFFF0000u);
}

// ---- K12F: fused convert + layer1 + layer2 via split-bf16 MFMA. ----
// grid = 384 = 3m x 16 hs(64-h slice) x 8 rt(16 rows); 256 thr = 4 waves.
// Each block converts its own x/W1/W2 slices fp32 -> bf16 hi/lo, written to
// LDS in MFMA FRAGMENT ORDER ((tile*64+lane)*16B): ds_write and frag ds_read
// are both linear & conflict-free by construction. W staged in 16-tile
// chunks (52 KB LDS). MFMA schedule / ts swizzle / D layout / opart layout
// identical to the R7-verified k12m. err ~2^-16 rel (lo*lo dropped).
__global__ __launch_bounds__(256) void k12f(
    const float* __restrict__ x,
    const float* __restrict__ Wf1, const float* __restrict__ bf1,
    const float* __restrict__ Wg1, const float* __restrict__ bg1,
    const float* __restrict__ Wk1, const float* __restrict__ bk1,
    const float* __restrict__ Wf2, const float* __restrict__ bf2,
    const float* __restrict__ Wg2, const float* __restrict__ bg2,
    const float* __restrict__ Wk2, const float* __restrict__ bk2,
    float* __restrict__ sk, float* __restrict__ opart)
{
    const int bx  = blockIdx.x;
    const int sid = (bx & 7) * 48 + (bx >> 3);   // bijective XCD swizzle
    const int m   = sid >> 7;          // 0..2
    const int rem = sid & 127;
    const int hs  = rem >> 3;          // 0..15  64-h slice (= opart k-slice)
    const int rt  = rem & 7;           // 0..7   16-row tile
    const int t = threadIdx.x, w = t >> 6, l = t & 63;
    const int col = l & 15, g = l >> 4;
    const int r0 = rt * 16;

    const float* W1 = (m == 0) ? Wf1 : (m == 1) ? Wg1 : Wk1;
    const float* b1 = (m == 0) ? bf1 : (m == 1) ? bg1 : bk1;
    const float* W2 = (m == 0) ? Wf2 : (m == 1) ? Wg2 : Wk2;
    const float* b2 = (m == 0) ? bf2 : (m == 1) ? bg2 : bk2;

    __shared__ __align__(16) ushort xfh[4096], xfl[4096];   // 8+8 KB X frags
    __shared__ __align__(16) ushort wfh[8192], wfl[8192];   // 16+16 KB W chunk
    __shared__ __align__(16) ushort tsh[1024], tsl[1024];   // 2+2 KB tanh

    // ---- X conversion: 8 ks-tiles -> frag-order LDS (linear writes) ----
    #pragma unroll
    for (int p = 0; p < 2; ++p) {
        const int u  = t + 256 * p;              // 0..511 = tile*64 + lane
        const int ks = u >> 6, ll = u & 63;
        const float* src = x + (r0 + (ll & 15)) * N_ + ks * 32 + (ll >> 4) * 8;
        const float4 a = *(const float4*)src;
        const float4 b = *(const float4*)(src + 4);
        const float s[8] = {a.x, a.y, a.z, a.w, b.x, b.y, b.z, b.w};
        union { short8v v; ushort q[8]; } Hh, Ll;
        #pragma unroll
        for (int i = 0; i < 8; ++i) {
            Hh.q[i] = bhi(s[i]);
            Ll.q[i] = bhi(s[i] - btrunc(s[i]));
        }
        *(short8v*)(xfh + u * 8) = Hh.v;
        *(short8v*)(xfl + u * 8) = Ll.v;
    }

    // ---- layer 1: D[16r x 16h/wave] over K=256, 2 chunks x 4 ksteps ----
    f32x4 acc1 = {0.f, 0.f, 0.f, 0.f};
    #pragma unroll
    for (int kc = 0; kc < 2; ++kc) {
        #pragma unroll
        for (int p = 0; p < 4; ++p) {            // stage W1 chunk (16 tiles)
            const int u    = t + 256 * p;        // tile = htl*4 + ksl
            const int tile = u >> 6, ll = u & 63;
            const int row  = hs * 64 + (tile >> 2) * 16 + (ll & 15);
            const int k    = (kc * 4 + (tile & 3)) * 32 + (ll >> 4) * 8;
            const float* src = W1 + row * N_ + k;
            const float4 a = *(const float4*)src;
            const float4 b = *(const float4*)(src + 4);
            const float s[8] = {a.x, a.y, a.z, a.w, b.x, b.y, b.z, b.w};
            union { short8v v; ushort q[8]; } Hh, Ll;
            #pragma unroll
            for (int i = 0; i < 8; ++i) {
                Hh.q[i] = bhi(s[i]);
                Ll.q[i] = bhi(s[i] - btrunc(s[i]));
            }
            *(short8v*)(wfh + u * 8) = Hh.v;
            *(short8v*)(wfl + u * 8) = Ll.v;
        }
        __syncthreads();
        #pragma unroll
        for (int ksl = 0; ksl < 4; ++ksl) {
            const short8v axh = *(const short8v*)(xfh + ((kc * 4 + ksl) * 64 + l) * 8);
            const short8v axl = *(const short8v*)(xfl + ((kc * 4 + ksl) * 64 + l) * 8);
            const short8v bh  = *(const short8v*)(wfh + ((w * 4 + ksl) * 64 + l) * 8);
            const short8v bl  = *(const short8v*)(wfl + ((w * 4 + ksl) * 64 + l) * 8);
            acc1 = __builtin_amdgcn_mfma_f32_16x16x32_bf16(axl, bh, acc1, 0, 0, 0);
            acc1 = __builtin_amdgcn_mfma_f32_16x16x32_bf16(axh, bl, acc1, 0, 0, 0);
            acc1 = __builtin_amdgcn_mfma_f32_16x16x32_bf16(axh, bh, acc1, 0, 0, 0);
        }
        __syncthreads();                         // before restage / ts phase
    }

    // ---- tanh + ts (swizzled, R7 layout) + sk ----
    {
        const int htile = hs * 4 + w;
        const int h  = htile * 16 + col;
        const float bv = b1[h];
        const int hl_ = w * 16 + col;            // h within 64-slice
        const int cb = hl_ >> 3, wi = hl_ & 7;
        #pragma unroll
        for (int j = 0; j < 4; ++j) {
            const int row = g * 4 + j;           // D: col=l&15, row=(l>>4)*4+j
            const float v = tanhf(acc1[j] + bv);
            if (m == 2) sk[(r0 + row) * H_ + h] = 1.0f - v * v;
            const int cs = cb ^ (row & 7);       // XOR-swizzle (T2)
            tsh[row * 64 + cs * 8 + wi] = bhi(v);
            tsl[row * 64 + cs * 8 + wi] = bhi(v - btrunc(v));
        }
    }
    __syncthreads();

    // ---- layer 2: D[16r x 64i/wave] over this 64-h slice, 2 chunks ----
    f32x4 acc2[4] = {{0.f,0.f,0.f,0.f}, {0.f,0.f,0.f,0.f},
                     {0.f,0.f,0.f,0.f}, {0.f,0.f,0.f,0.f}};
    #pragma unroll
    for (int hkl = 0; hkl < 2; ++hkl) {
        #pragma unroll
        for (int p = 0; p < 4; ++p) {            // stage W2 chunk (16 itiles)
            const int u    = t + 256 * p;
            const int tile = u >> 6, ll = u & 63;
            const int i    = tile * 16 + (ll & 15);
            const int kh   = (hs * 2 + hkl) * 32 + (ll >> 4) * 8;
            const float* src = W2 + i * H_ + kh;
            const float4 a = *(const float4*)src;
            const float4 b = *(const float4*)(src + 4);
            const float s[8] = {a.x, a.y, a.z, a.w, b.x, b.y, b.z, b.w};
            union { short8v v; ushort q[8]; } Hh, Ll;
            #pragma unroll
            for (int i2 = 0; i2 < 8; ++i2) {
                Hh.q[i2] = bhi(s[i2]);
                Ll.q[i2] = bhi(s[i2] - btrunc(s[i2]));
            }
            *(short8v*)(wfh + u * 8) = Hh.v;
            *(short8v*)(wfl + u * 8) = Ll.v;
        }
        __syncthreads();
        const int cs = (hkl * 4 + g) ^ (col & 7);         // A row = col
        const short8v ath = *(const short8v*)(tsh + col * 64 + cs * 8);
        const short8v atl = *(const short8v*)(tsl + col * 64 + cs * 8);
        #pragma unroll
        for (int n = 0; n < 4; ++n) {
            const short8v bh = *(const short8v*)(wfh + ((w * 4 + n) * 64 + l) * 8);
            const short8v bl = *(const short8v*)(wfl + ((w * 4 + n) * 64 + l) * 8);
            acc2[n] = __builtin_amdgcn_mfma_f32_16x16x32_bf16(atl, bh, acc2[n], 0, 0, 0);
            acc2[n] = __builtin_amdgcn_mfma_f32_16x16x32_bf16(ath, bl, acc2[n], 0, 0, 0);
            acc2[n] = __builtin_amdgcn_mfma_f32_16x16x32_bf16(ath, bh, acc2[n], 0, 0, 0);
        }
        __syncthreads();                         // before restage
    }

    #pragma unroll
    for (int n = 0; n < 4; ++n) {
        const int i = (w * 4 + n) * 16 + col;
        const float bias = (hs == 0) ? b2[i] : 0.0f;
        #pragma unroll
        for (int j = 0; j < 4; ++j) {
            const int row = g * 4 + j;
            opart[((hs * 3 + m) * BS_ + r0 + row) * N_ + i] = acc2[n][j] + bias;
        }
    }
}

// ---- K3S: fused v+J partials; sums opart inline (replaces k25+k3). ----
// grid = 512. Inline-sum logic proven in R3-P3; rest identical to R0 k3.
__global__ __launch_bounds__(256) void k3s(
    const float* __restrict__ Wk1, const float* __restrict__ Wk2,
    const float* __restrict__ opart, const float* __restrict__ sk,
    float* __restrict__ jpart)
{
    const int q  = blockIdx.x & 15;    // 0..15 h-slice
    const int rp = blockIdx.x >> 4;    // 0..31 row tile
    const int t  = threadIdx.x;
    const int r0 = rp * 4;
    const int h0 = q * 64;

    __shared__ float fos[4][256], gos[4][256];   // 8 KB
    __shared__ float sfv[4][64], sgv[4][64];     // 2 KB

    // stage reduced fo/go rows straight from opart (coalesced over i)
    for (int u = t; u < 1024; u += 256) {
        const int r = u >> 8, i = u & 255;
        float sf = 0.f, sg = 0.f;
        #pragma unroll
        for (int ks = 0; ks < 16; ++ks) {
            sf += opart[((ks * 3 + 0) * BS_ + r0 + r) * N_ + i];
            sg += opart[((ks * 3 + 1) * BS_ + r0 + r) * N_ + i];
        }
        fos[r][i] = sf; gos[r][i] = sg;
    }
    __syncthreads();

    {
        const int hl = t & 63;
        const int rl = t >> 6;         // 0..3, wave-uniform
        const int h  = h0 + hl;
        const float* w2 = Wk2 + h;
        float vf = 0.f, vg = 0.f;
        #pragma unroll 8
        for (int c = 0; c < 64; ++c) {
            const float4 of = ((const float4*)fos[rl])[c];
            const float4 og = ((const float4*)gos[rl])[c];
            const float w0  = w2[(4 * c + 0) * H_];
            const float w1v = w2[(4 * c + 1) * H_];
            const float w2v = w2[(4 * c + 2) * H_];
            const float w3  = w2[(4 * c + 3) * H_];
            vf += of.x * w0 + of.y * w1v + of.z * w2v + of.w * w3;
            vg += og.x * w0 + og.y * w1v + og.z * w2v + og.w * w3;
        }
        const float s = sk[(r0 + rl) * H_ + h];
        sfv[rl][hl] = s * vf;
        sgv[rl][hl] = s * vg;
    }
    __syncthreads();

    {
        float jf[4] = {0.f, 0.f, 0.f, 0.f};
        float jg[4] = {0.f, 0.f, 0.f, 0.f};
        const float* w1 = Wk1 + h0 * N_ + t;    // coalesced over t
        #pragma unroll 4
        for (int c = 0; c < 16; ++c) {
            const float w0  = w1[(4 * c + 0) * N_];
            const float wv1 = w1[(4 * c + 1) * N_];
            const float wv2 = w1[(4 * c + 2) * N_];
            const float wv3 = w1[(4 * c + 3) * N_];
            #pragma unroll
            for (int r = 0; r < 4; ++r) {
                const float4 sf = ((const float4*)sfv[r])[c];
                const float4 sg = ((const float4*)sgv[r])[c];
                jf[r] += sf.x * w0 + sf.y * wv1 + sf.z * wv2 + sf.w * wv3;
                jg[r] += sg.x * w0 + sg.y * wv1 + sg.z * wv2 + sg.w * wv3;
            }
        }
        #pragma unroll
        for (int r = 0; r < 4; ++r) {
            jpart[((q * 2 + 0) * BS_ + r0 + r) * N_ + t] = jf[r];
            jpart[((q * 2 + 1) * BS_ + r0 + r) * N_ + t] = jg[r];
        }
    }
}

// ---- K4S: final reduce (opart inline) + norms + mask + output. grid=128 ----
__global__ __launch_bounds__(256) void k4s(
    const float* __restrict__ opart,
    const float* __restrict__ jpart,
    float* __restrict__ out)
{
    const int r = blockIdx.x;
    const int t = threadIdx.x;
    __shared__ float red[12];

    float fo = 0.f, go = 0.f, ko = 0.f;
    #pragma unroll
    for (int ks = 0; ks < 16; ++ks) {
        fo += opart[((ks * 3 + 0) * BS_ + r) * N_ + t];
        go += opart[((ks * 3 + 1) * BS_ + r) * N_ + t];
        ko += opart[((ks * 3 + 2) * BS_ + r) * N_ + t];
    }

    float jf = 0.f, jg = 0.f;
    #pragma unroll
    for (int q = 0; q < 16; ++q) {
        jf += jpart[((q * 2 + 0) * BS_ + r) * N_ + t];
        jg += jpart[((q * 2 + 1) * BS_ + r) * N_ + t];
    }

    float v0 = ko * ko, v1 = jf * jf, v2 = ko * jg;
    #pragma unroll
    for (int o = 32; o > 0; o >>= 1) {
        v0 += __shfl_xor(v0, o, 64);
        v1 += __shfl_xor(v1, o, 64);
        v2 += __shfl_xor(v2, o, 64);
    }
    const int wid = t >> 6;
    if ((t & 63) == 0) {
        red[wid * 3 + 0] = v0;
        red[wid * 3 + 1] = v1;
        red[wid * 3 + 2] = v2;
    }
    __syncthreads();
    const float kn2 = red[0] + red[3] + red[6] + red[9];
    const float jf2 = red[1] + red[4] + red[7] + red[10];
    const float kjg = red[2] + red[5] + red[8] + red[11];

    const float knorm = sqrtf(kn2);
    const float kn4 = kn2 * kn2;
    const float kn8 = kn4 * kn4;
    const float c1 = sqrtf(jf2) - 60.0f * kn8 * knorm;
    const float c2 = kjg - 20.0f * kn8 * kn2;
    const float scale = ((c1 > 1e-8f) || (c2 < -1e-8f)) ? 0.5f : 1.0f;

    out[r * N_ + t] = (fo + go) * scale;
}

// ================= fallback: round-2 proven fused kernel =================
__global__ __launch_bounds__(256) void manifold_fused(
    const float* __restrict__ x,
    const float* __restrict__ Wf1, const float* __restrict__ bf1v,
    const float* __restrict__ Wf2, const float* __restrict__ bf2v,
    const float* __restrict__ Wg1, const float* __restrict__ bg1v,
    const float* __restrict__ Wg2, const float* __restrict__ bg2v,
    const float* __restrict__ Wk1, const float* __restrict__ bk1v,
    const float* __restrict__ Wk2, const float* __restrict__ bk2v,
    float* __restrict__ out)
{
    const int b = blockIdx.x;
    const int t = threadIdx.x;
    __shared__ float xs[N_];
    __shared__ float tf[H_], tg[H_], tk[H_], sk[H_];
    __shared__ float fo[N_], go[N_];
    __shared__ float sfv[H_], sgv[H_];
    __shared__ float red[12];

    xs[t] = x[b * N_ + t];
    __syncthreads();
    {
        float acc[12];
        const float4* rows[12];
        #pragma unroll
        for (int m = 0; m < 4; ++m) {
            const int h = t + m * 256;
            rows[m]     = (const float4*)(Wf1 + h * N_);
            rows[4 + m] = (const float4*)(Wg1 + h * N_);
            rows[8 + m] = (const float4*)(Wk1 + h * N_);
            acc[m] = bf1v[h]; acc[4 + m] = bg1v[h]; acc[8 + m] = bk1v[h];
        }
        const float4* xs4 = (const float4*)xs;
        #pragma unroll 2
        for (int c = 0; c < 64; ++c) {
            float4 a = xs4[c];
            #pragma unroll
            for (int r = 0; r < 12; ++r) {
                float4 w = rows[r][c];
                acc[r] += w.x * a.x + w.y * a.y + w.z * a.z + w.w * a.w;
            }
        }
        #pragma unroll
        for (int m = 0; m < 4; ++m) {
            const int h = t + m * 256;
            float vtf = tanhf(acc[m]);
            float vtg = tanhf(acc[4 + m]);
            float vtk = tanhf(acc[8 + m]);
            tf[h] = vtf; tg[h] = vtg; tk[h] = vtk; sk[h] = 1.0f - vtk * vtk;
        }
    }
    __syncthreads();
    float af = bf2v[t], ag = bg2v[t], ak = bk2v[t];
    {
        const float4* rf = (const float4*)(Wf2 + t * H_);
        const float4* rg = (const float4*)(Wg2 + t * H_);
        const float4* rk = (const float4*)(Wk2 + t * H_);
        #pragma unroll 2
        for (int c = 0; c < 256; ++c) {
            float4 wf = rf[c], wg = rg[c], wk = rk[c];
            float4 vf = ((const float4*)tf)[c];
            af += wf.x*vf.x + wf.y*vf.y + wf.z*vf.z + wf.w*vf.w;
            float4 vg = ((const float4*)tg)[c];
            ag += wg.x*vg.x + wg.y*vg.y + wg.z*vg.z + wg.w*vg.w;
            float4 vk = ((const float4*)tk)[c];
            ak += wk.x*vk.x + wk.y*vk.y + wk.z*vk.z + wk.w*vk.w;
        }
    }
    fo[t] = af; go[t] = ag;
    __syncthreads();
    {
        float vf[4] = {0.f,0.f,0.f,0.f}, vg[4] = {0.f,0.f,0.f,0.f};
        const float* base = Wk2 + 4 * t;
        #pragma unroll 4
        for (int i = 0; i < N_; ++i) {
            float4 w = *(const float4*)(base + i * H_);
            float fv = fo[i], gv = go[i];
            vf[0]+=w.x*fv; vf[1]+=w.y*fv; vf[2]+=w.z*fv; vf[3]+=w.w*fv;
            vg[0]+=w.x*gv; vg[1]+=w.y*gv; vg[2]+=w.z*gv; vg[3]+=w.w*gv;
        }
        #pragma unroll
        for (int c = 0; c < 4; ++c) {
            sfv[4*t+c] = sk[4*t+c]*vf[c];
            sgv[4*t+c] = sk[4*t+c]*vg[c];
        }
    }
    __syncthreads();
    float jf = 0.f, jg = 0.f;
    {
        const float* col = Wk1 + t;
        #pragma unroll 4
        for (int c = 0; c < 256; ++c) {
            float4 s4 = ((const float4*)sfv)[c];
            float4 g4 = ((const float4*)sgv)[c];
            const int h = c * 4;
            float w0 = col[(h+0)*N_], w1 = col[(h+1)*N_];
            float w2 = col[(h+2)*N_], w3 = col[(h+3)*N_];
            jf += s4.x*w0 + s4.y*w1 + s4.z*w2 + s4.w*w3;
            jg += g4.x*w0 + g4.y*w1 + g4.z*w2 + g4.w*w3;
        }
    }
    float v0 = ak*ak, v1 = jf*jf, v2 = ak*jg;
    #pragma unroll
    for (int o = 32; o > 0; o >>= 1) {
        v0 += __shfl_xor(v0, o, 64);
        v1 += __shfl_xor(v1, o, 64);
        v2 += __shfl_xor(v2, o, 64);
    }
    const int wid = t >> 6;
    if ((t & 63) == 0) {
        red[wid*3+0] = v0; red[wid*3+1] = v1; red[wid*3+2] = v2;
    }
    __syncthreads();
    const float kn2 = red[0]+red[3]+red[6]+red[9];
    const float jf2 = red[1]+red[4]+red[7]+red[10];
    const float kjg = red[2]+red[5]+red[8]+red[11];
    const float knorm = sqrtf(kn2);
    const float kn4 = kn2*kn2, kn8 = kn4*kn4;
    const float c1 = sqrtf(jf2) - 60.0f*kn8*knorm;
    const float c2 = kjg - 20.0f*kn8*kn2;
    const float scale = ((c1 > 1e-8f) || (c2 < -1e-8f)) ? 0.5f : 1.0f;
    out[b*N_+t] = (af+ag)*scale;
}

extern "C" void kernel_launch(void* const* d_in, const int* in_sizes, int n_in,
                              void* d_out, int out_size, void* d_ws, size_t ws_size,
                              hipStream_t stream) {
    const float* x    = (const float*)d_in[1];
    const float* Wf1  = (const float*)d_in[2];
    const float* bf1v = (const float*)d_in[3];
    const float* Wf2  = (const float*)d_in[4];
    const float* bf2v = (const float*)d_in[5];
    const float* Wg1  = (const float*)d_in[6];
    const float* bg1v = (const float*)d_in[7];
    const float* Wg2  = (const float*)d_in[8];
    const float* bg2v = (const float*)d_in[9];
    const float* Wk1  = (const float*)d_in[10];
    const float* bk1v = (const float*)d_in[11];
    const float* Wk2  = (const float*)d_in[12];
    const float* bk2v = (const float*)d_in[13];
    float* out = (float*)d_out;

    if (ws_size < (size_t)WS_FLOATS * sizeof(float)) {
        manifold_fused<<<BS_, 256, 0, stream>>>(
            x, Wf1, bf1v, Wf2, bf2v, Wg1, bg1v, Wg2, bg2v,
            Wk1, bk1v, Wk2, bk2v, out);
        return;
    }

    float* ws    = (float*)d_ws;
    float* sk    = ws + WS_SK;
    float* opart = ws + WS_OPART;
    float* jpart = ws + WS_JPART;

    k12f<<<384, 256, 0, stream>>>(x, Wf1, bf1v, Wg1, bg1v, Wk1, bk1v,
                                  Wf2, bf2v, Wg2, bg2v, Wk2, bk2v,
                                  sk, opart);
    k3s <<<512, 256, 0, stream>>>(Wk1, Wk2, opart, sk, jpart);
    k4s <<<BS_, 256, 0, stream>>>(opart, jpart, out);
}